// Round 1
// baseline (4192.743 us; speedup 1.0000x reference)
//
#include <hip/hip_runtime.h>

// NHWC conv 3x3 stride1 SAME: x[16,128,128,64] f32, w[3,3,64,128] f32, bias[128]
// out[16,128,128,128] f32. Round 0: correctness baseline, 1 thread/output.
// Layout choice: co = low 7 bits of global index -> weight loads coalesced
// across lanes, x loads wave-uniform broadcast.

#define HH 128
#define WW 128
#define CIN 64
#define COUT 128

__global__ __launch_bounds__(256) void conv3x3_direct(
    const float* __restrict__ x,
    const float* __restrict__ wgt,
    const float* __restrict__ bias,
    float* __restrict__ out)
{
    int idx = blockIdx.x * 256 + threadIdx.x;
    int co = idx & (COUT - 1);
    int w  = (idx >> 7) & (WW - 1);
    int h  = (idx >> 14) & (HH - 1);
    int n  = idx >> 21;

    float acc = bias[co];

    #pragma unroll
    for (int kh = 0; kh < 3; ++kh) {
        int ih = h + kh - 1;
        if (ih < 0 || ih >= HH) continue;
        #pragma unroll
        for (int kw = 0; kw < 3; ++kw) {
            int iw = w + kw - 1;
            if (iw < 0 || iw >= WW) continue;
            const float* __restrict__ xp =
                x + (((size_t)(n * HH + ih) * WW + iw) * CIN);
            const float* __restrict__ wp =
                wgt + ((size_t)((kh * 3 + kw) * CIN)) * COUT + co;
            #pragma unroll 8
            for (int ci = 0; ci < CIN; ++ci)
                acc = fmaf(xp[ci], wp[(size_t)ci * COUT], acc);
        }
    }
    out[idx] = acc;
}

extern "C" void kernel_launch(void* const* d_in, const int* in_sizes, int n_in,
                              void* d_out, int out_size, void* d_ws, size_t ws_size,
                              hipStream_t stream)
{
    const float* x    = (const float*)d_in[0];
    const float* wgt  = (const float*)d_in[1];
    const float* bias = (const float*)d_in[2];
    float* out = (float*)d_out;

    // 16*128*128*128 = 33,554,432 outputs, 256 threads/block
    int total = out_size;              // 33554432
    int blocks = (total + 255) / 256;  // 131072
    conv3x3_direct<<<blocks, 256, 0, stream>>>(x, wgt, bias, out);
}

// Round 2
// 324.525 us; speedup vs baseline: 12.9196x; 12.9196x over previous
//
#include <hip/hip_runtime.h>

// NHWC conv 3x3 stride-1 SAME: x[16,128,128,64] f32, w[3,3,64,128] f32,
// bias[128] f32 -> out[16,128,128,128] f32.
// Implicit GEMM in bf16 MFMA (16x16x32): per block = one image row,
// 128 pixels x 128 couts, 4 waves (2x2), each wave 64x64 (4x4 tiles of 16x16).
// A and B fragments loaded directly from global (no LDS): weights are L1/L2
// hot (144 KB), x rows served from L2.

#define HH 128
#define WW 128
#define CIN 64
#define COUT 128

typedef __attribute__((ext_vector_type(8))) short v8s;   // 8 bf16 = 4 VGPRs
typedef __attribute__((ext_vector_type(4))) float v4f;   // MFMA C/D

// byte offset of bf16 x inside d_ws (after 147456 B of transposed weights,
// rounded up to leave >=128 B under-run slack before x and 256 B after)
#define XOFF_BYTES 151552
#define WS_NEEDED  (XOFF_BYTES + 16u*HH*WW*CIN*2u + 256u)

static __device__ __forceinline__ unsigned short f2bf(float f) {
    unsigned int u = __float_as_uint(f);
    unsigned int r = (u + 0x7fffu + ((u >> 16) & 1u)) >> 16;   // RNE
    return (unsigned short)r;
}

// ---- pre-pass: x fp32 -> bf16 (same NHWC layout), 8 elems/thread ----
__global__ __launch_bounds__(256) void cvt_x(const float4* __restrict__ in,
                                             uint4* __restrict__ out, int n8) {
    int i = blockIdx.x * 256 + threadIdx.x;
    if (i >= n8) return;
    float4 a = in[2 * i], b = in[2 * i + 1];
    uint4 r;
    r.x = (unsigned)f2bf(a.x) | ((unsigned)f2bf(a.y) << 16);
    r.y = (unsigned)f2bf(a.z) | ((unsigned)f2bf(a.w) << 16);
    r.z = (unsigned)f2bf(b.x) | ((unsigned)f2bf(b.y) << 16);
    r.w = (unsigned)f2bf(b.z) | ((unsigned)f2bf(b.w) << 16);
    out[i] = r;
}

// ---- pre-pass: w[tap][ci][co] fp32 -> w_t[tap][co][ci] bf16 ----
__global__ __launch_bounds__(256) void cvt_w(const float* __restrict__ wgt,
                                             unsigned short* __restrict__ wt) {
    int idx = blockIdx.x * 256 + threadIdx.x;   // < 9*64*128 = 73728
    if (idx >= 9 * CIN * COUT) return;
    int co  = idx & (COUT - 1);
    int ci  = (idx >> 7) & (CIN - 1);
    int tap = idx >> 13;
    wt[(tap * COUT + co) * CIN + ci] = f2bf(wgt[idx]);
}

// ---- main: implicit-GEMM MFMA conv ----
__global__ __launch_bounds__(256, 3) void conv_mfma(
    const unsigned short* __restrict__ xb,  // bf16 [16,128,128,64]
    const unsigned short* __restrict__ wt,  // bf16 [9,128,64]
    const float* __restrict__ bias,
    float* __restrict__ out) {
    int bid = blockIdx.x;          // 0..2047 = n*128 + h
    int h = bid & (HH - 1);
    int n = bid >> 7;
    int tid  = threadIdx.x;
    int lane = tid & 63;
    int wid  = tid >> 6;           // 0..3
    int wi = wid >> 1;             // pixel half (0/1)
    int wj = wid & 1;              // cout half (0/1)
    int l15  = lane & 15;
    int quad = lane >> 4;
    int pixelL = wi * 64 + l15;    // this lane's base pixel (m index)
    int ciL    = quad * 8;         // this lane's k sub-offset

    v4f acc[4][4];
    #pragma unroll
    for (int i = 0; i < 4; ++i)
        #pragma unroll
        for (int j = 0; j < 4; ++j) acc[i][j] = (v4f)0.f;

    #pragma unroll
    for (int dh = 0; dh < 3; ++dh) {
        int ih = h + dh - 1;
        if (ih < 0 || ih >= HH) continue;    // block-uniform skip
        const unsigned short* xrow = xb + ((size_t)(n * HH + ih)) * WW * CIN;
        #pragma unroll
        for (int dw = 0; dw < 3; ++dw) {
            const unsigned short* wtap = wt + (dh * 3 + dw) * COUT * CIN;
            #pragma unroll
            for (int kc = 0; kc < 2; ++kc) {
                int kb = kc * 32;
                v8s bfrag[4];
                #pragma unroll
                for (int t = 0; t < 4; ++t) {
                    int co = wj * 64 + t * 16 + l15;
                    bfrag[t] = *(const v8s*)(wtap + co * CIN + kb + ciL);
                }
                v8s afrag[4];
                #pragma unroll
                for (int t = 0; t < 4; ++t) {
                    int iw = pixelL + t * 16 + dw - 1;   // may be -1 or 128
                    v8s av = *(const v8s*)(xrow + (ptrdiff_t)iw * CIN + kb + ciL);
                    if ((unsigned)iw >= (unsigned)WW) av = (v8s)(short)0;
                    afrag[t] = av;
                }
                #pragma unroll
                for (int ti = 0; ti < 4; ++ti)
                    #pragma unroll
                    for (int tj = 0; tj < 4; ++tj)
                        acc[ti][tj] = __builtin_amdgcn_mfma_f32_16x16x32_bf16(
                            afrag[ti], bfrag[tj], acc[ti][tj], 0, 0, 0);
            }
        }
    }

    float bv[4];
    #pragma unroll
    for (int tj = 0; tj < 4; ++tj) bv[tj] = bias[wj * 64 + tj * 16 + l15];

    float* orow = out + ((size_t)(n * HH + h)) * WW * COUT;
    #pragma unroll
    for (int ti = 0; ti < 4; ++ti) {
        #pragma unroll
        for (int r = 0; r < 4; ++r) {
            int p = wi * 64 + ti * 16 + quad * 4 + r;    // C/D: row=quad*4+reg
            float* op = orow + (size_t)p * COUT + wj * 64 + l15;  // col=lane&15
            #pragma unroll
            for (int tj = 0; tj < 4; ++tj)
                op[tj * 16] = acc[ti][tj][r] + bv[tj];
        }
    }
}

// ---- fallback (round-0 direct conv) if workspace is too small ----
__global__ __launch_bounds__(256) void conv3x3_direct(
    const float* __restrict__ x, const float* __restrict__ wgt,
    const float* __restrict__ bias, float* __restrict__ out) {
    int idx = blockIdx.x * 256 + threadIdx.x;
    int co = idx & (COUT - 1);
    int w  = (idx >> 7) & (WW - 1);
    int h  = (idx >> 14) & (HH - 1);
    int n  = idx >> 21;
    float acc = bias[co];
    #pragma unroll
    for (int kh = 0; kh < 3; ++kh) {
        int ih = h + kh - 1;
        if (ih < 0 || ih >= HH) continue;
        #pragma unroll
        for (int kw = 0; kw < 3; ++kw) {
            int iw = w + kw - 1;
            if (iw < 0 || iw >= WW) continue;
            const float* xp = x + (((size_t)(n * HH + ih) * WW + iw) * CIN);
            const float* wp = wgt + ((size_t)((kh * 3 + kw) * CIN)) * COUT + co;
            #pragma unroll 8
            for (int ci = 0; ci < CIN; ++ci)
                acc = fmaf(xp[ci], wp[(size_t)ci * COUT], acc);
        }
    }
    out[idx] = acc;
}

extern "C" void kernel_launch(void* const* d_in, const int* in_sizes, int n_in,
                              void* d_out, int out_size, void* d_ws, size_t ws_size,
                              hipStream_t stream) {
    const float* x    = (const float*)d_in[0];
    const float* wgt  = (const float*)d_in[1];
    const float* bias = (const float*)d_in[2];
    float* out = (float*)d_out;

    if (ws_size < (size_t)WS_NEEDED) {
        int blocks = (out_size + 255) / 256;
        conv3x3_direct<<<blocks, 256, 0, stream>>>(x, wgt, bias, out);
        return;
    }

    unsigned short* wt = (unsigned short*)d_ws;
    unsigned short* xb = (unsigned short*)((char*)d_ws + XOFF_BYTES);

    // weights: 73728 elems
    cvt_w<<<(9 * CIN * COUT + 255) / 256, 256, 0, stream>>>(wgt, wt);
    // x: 16777216 floats -> 2097152 x 8-elem groups
    int n8 = 16 * HH * WW * CIN / 8;
    cvt_x<<<(n8 + 255) / 256, 256, 0, stream>>>(
        (const float4*)x, (uint4*)xb, n8);
    // main conv: one block per (n,h) row
    conv_mfma<<<16 * HH, 256, 0, stream>>>(xb, wt, bias, out);
}

// Round 3
// 254.402 us; speedup vs baseline: 16.4808x; 1.2756x over previous
//
#include <hip/hip_runtime.h>

// NHWC conv 3x3 stride-1 SAME: x[16,128,128,64] f32, w[3,3,64,128] f32,
// bias[128] f32 -> out[16,128,128,128] f32.
// Implicit GEMM, bf16 MFMA 16x16x32. Block = one image row (128 px x 128 co),
// 4 waves in 2x2, each wave 64x64 (4x4 of 16x16 tiles).
// Round 2: 3 input rows staged in LDS (fp32->bf16 on the fly, xor-swizzled
// to kill bank conflicts, zeroed 1-px borders), B (transposed weights) from
// global/L2, XCD-aware block remap.

#define HH 128
#define WW 128
#define CIN 64
#define COUT 128

typedef __attribute__((ext_vector_type(8))) short v8s;   // 8 bf16 = 16 B
typedef __attribute__((ext_vector_type(4))) float v4f;   // MFMA C/D

#define ROW_CHUNKS 1040            // 130 px * 8 chunks(16B) per px
#define WS_NEEDED  (9u * CIN * COUT * 2u)   // transposed bf16 weights

static __device__ __forceinline__ unsigned short f2bf(float f) {
    unsigned int u = __float_as_uint(f);
    unsigned int r = (u + 0x7fffu + ((u >> 16) & 1u)) >> 16;   // RNE
    return (unsigned short)r;
}

// ---- pre-pass: w[tap][ci][co] fp32 -> w_t[tap][co][ci] bf16 ----
__global__ __launch_bounds__(256) void cvt_w(const float* __restrict__ wgt,
                                             unsigned short* __restrict__ wt) {
    int idx = blockIdx.x * 256 + threadIdx.x;   // < 9*64*128 = 73728
    if (idx >= 9 * CIN * COUT) return;
    int co  = idx & (COUT - 1);
    int ci  = (idx >> 7) & (CIN - 1);
    int tap = idx >> 13;
    wt[(tap * COUT + co) * CIN + ci] = f2bf(wgt[idx]);
}

// ---- main: implicit-GEMM MFMA conv with LDS row staging ----
__global__ __launch_bounds__(256, 3) void conv_mfma(
    const float* __restrict__ x,            // fp32 [16,128,128,64]
    const unsigned short* __restrict__ wt,  // bf16 [9,128,64] (tap,co,ci)
    const float* __restrict__ bias,
    float* __restrict__ out) {
    __shared__ v8s smem[3 * ROW_CHUNKS];    // 49,920 B

    // XCD-aware remap: consecutive h on same XCD (blockIdx%8 ~ XCD id)
    int bid = blockIdx.x;                   // 0..2047
    int logical = ((bid & 7) << 8) | (bid >> 3);
    int h = logical & (HH - 1);
    int n = logical >> 7;

    int tid  = threadIdx.x;
    int lane = tid & 63;
    int wid  = tid >> 6;           // 0..3
    int wi = wid >> 1;             // pixel half (0/1)
    int wj = wid & 1;              // cout half (0/1)
    int l15  = lane & 15;
    int quad = lane >> 4;
    int pixelL = wi * 64 + l15;    // lane's base pixel (m index)

    // ---- zero the 1-px borders (chunks 0..7 and 1032..1039 of each row) ----
    if (tid < 48) {
        int row = tid >> 4, k = tid & 15;
        int c = (k < 8) ? k : (1024 + k);          // 0..7 or 1032..1039
        smem[row * ROW_CHUNKS + c] = (v8s)(short)0;
    }

    // ---- stage valid rows: fp32 global -> bf16 LDS (swizzled) ----
    #pragma unroll
    for (int dh = 0; dh < 3; ++dh) {
        int ih = h + dh - 1;
        if (ih < 0 || ih >= HH) continue;          // block-uniform
        const float* rowf = x + ((size_t)(n * HH + ih)) * WW * CIN;
        #pragma unroll
        for (int k = 0; k < 4; ++k) {
            int c = 8 + tid + (k << 8);            // data chunk 8..1031
            const float* p = rowf + (size_t)(c - 8) * 8;
            float4 a = *(const float4*)p;
            float4 b = *(const float4*)(p + 4);
            v8s ch;
            ch[0] = (short)f2bf(a.x); ch[1] = (short)f2bf(a.y);
            ch[2] = (short)f2bf(a.z); ch[3] = (short)f2bf(a.w);
            ch[4] = (short)f2bf(b.x); ch[5] = (short)f2bf(b.y);
            ch[6] = (short)f2bf(b.z); ch[7] = (short)f2bf(b.w);
            int cp = c ^ ((c >> 3) & 7);           // xor-swizzle within px-group
            smem[dh * ROW_CHUNKS + cp] = ch;
        }
    }
    __syncthreads();

    v4f acc[4][4];
    #pragma unroll
    for (int i = 0; i < 4; ++i)
        #pragma unroll
        for (int j = 0; j < 4; ++j) acc[i][j] = (v4f)0.f;

    #pragma unroll
    for (int dh = 0; dh < 3; ++dh) {
        int ih = h + dh - 1;
        if (ih < 0 || ih >= HH) continue;          // block-uniform
        const v8s* srow = smem + dh * ROW_CHUNKS;
        #pragma unroll
        for (int dw = 0; dw < 3; ++dw) {
            const unsigned short* wtap = wt + (dh * 3 + dw) * COUT * CIN;
            #pragma unroll
            for (int kc = 0; kc < 2; ++kc) {
                v8s bfrag[4];
                #pragma unroll
                for (int t = 0; t < 4; ++t) {
                    int co = wj * 64 + t * 16 + l15;
                    bfrag[t] = *(const v8s*)(wtap + co * CIN + kc * 32 + quad * 8);
                }
                v8s afrag[4];
                #pragma unroll
                for (int t = 0; t < 4; ++t) {
                    int pl = pixelL + t * 16 + dw;     // 0..129, borders are 0
                    int c  = pl * 8 + kc * 4 + quad;
                    afrag[t] = srow[c ^ (pl & 7)];
                }
                #pragma unroll
                for (int ti = 0; ti < 4; ++ti)
                    #pragma unroll
                    for (int tj = 0; tj < 4; ++tj)
                        acc[ti][tj] = __builtin_amdgcn_mfma_f32_16x16x32_bf16(
                            afrag[ti], bfrag[tj], acc[ti][tj], 0, 0, 0);
            }
        }
    }

    float bv[4];
    #pragma unroll
    for (int tj = 0; tj < 4; ++tj) bv[tj] = bias[wj * 64 + tj * 16 + l15];

    float* orow = out + ((size_t)(n * HH + h)) * WW * COUT;
    #pragma unroll
    for (int ti = 0; ti < 4; ++ti) {
        #pragma unroll
        for (int r = 0; r < 4; ++r) {
            int p = wi * 64 + ti * 16 + quad * 4 + r;    // C/D: row=quad*4+reg
            float* op = orow + (size_t)p * COUT + wj * 64 + l15;  // col=lane&15
            #pragma unroll
            for (int tj = 0; tj < 4; ++tj)
                op[tj * 16] = acc[ti][tj][r] + bv[tj];
        }
    }
}

// ---- fallback (direct conv) if workspace is too small ----
__global__ __launch_bounds__(256) void conv3x3_direct(
    const float* __restrict__ x, const float* __restrict__ wgt,
    const float* __restrict__ bias, float* __restrict__ out) {
    int idx = blockIdx.x * 256 + threadIdx.x;
    int co = idx & (COUT - 1);
    int w  = (idx >> 7) & (WW - 1);
    int h  = (idx >> 14) & (HH - 1);
    int n  = idx >> 21;
    float acc = bias[co];
    #pragma unroll
    for (int kh = 0; kh < 3; ++kh) {
        int ih = h + kh - 1;
        if (ih < 0 || ih >= HH) continue;
        #pragma unroll
        for (int kw = 0; kw < 3; ++kw) {
            int iw = w + kw - 1;
            if (iw < 0 || iw >= WW) continue;
            const float* xp = x + (((size_t)(n * HH + ih) * WW + iw) * CIN);
            const float* wp = wgt + ((size_t)((kh * 3 + kw) * CIN)) * COUT + co;
            #pragma unroll 8
            for (int ci = 0; ci < CIN; ++ci)
                acc = fmaf(xp[ci], wp[(size_t)ci * COUT], acc);
        }
    }
    out[idx] = acc;
}

extern "C" void kernel_launch(void* const* d_in, const int* in_sizes, int n_in,
                              void* d_out, int out_size, void* d_ws, size_t ws_size,
                              hipStream_t stream) {
    const float* x    = (const float*)d_in[0];
    const float* wgt  = (const float*)d_in[1];
    const float* bias = (const float*)d_in[2];
    float* out = (float*)d_out;

    if (ws_size < (size_t)WS_NEEDED) {
        int blocks = (out_size + 255) / 256;
        conv3x3_direct<<<blocks, 256, 0, stream>>>(x, wgt, bias, out);
        return;
    }

    unsigned short* wt = (unsigned short*)d_ws;
    cvt_w<<<(9 * CIN * COUT + 255) / 256, 256, 0, stream>>>(wgt, wt);
    conv_mfma<<<16 * HH, 256, 0, stream>>>(x, wt, bias, out);
}